// Round 10
// baseline (34.498 us; speedup 1.0000x reference)
//
#include <hip/hip_runtime.h>
#include <math.h>

#define TSTEPS 11
#define PPB 7          // problems per 64-thread wave
#define LPP 9          // lanes per problem
#define IN_STRIDE 228  // per-problem input slot, floats (228%32=4 -> bank stagger)
                       // step t at t*20: [0]=dt, [2..7]=wa(6), [8..16]=Rm(9)
#define WSTRIDE 228    // per-problem work slot
// work region: U[9][20] at 0..179
// update:     PHT [18][8] at 0, S6 [6][8] at 144, Y at 192, EST at 200
#define PHT_OFF 0
#define S6_OFF 144
#define Y_OFF 192
#define EST_OFF 200

__device__ __forceinline__ float sel3(int c, float a, float b, float d) {
    float t = (c == 1) ? b : a;
    return (c == 2) ? d : t;
}

__device__ __forceinline__ size_t umin_sz(size_t a, size_t b) { return a < b ? a : b; }

__global__ void __launch_bounds__(64)
ekf_kernel(const float* __restrict__ dts, const float* __restrict__ wa,
           const float* __restrict__ Rc, const float* __restrict__ vel,
           const float* __restrict__ grav, const float* __restrict__ H0g,
           const float* __restrict__ H1g, const float* __restrict__ prot,
           const float* __restrict__ ptrans, const float* __restrict__ vrot,
           const float* __restrict__ vtrans, const float* __restrict__ vrstd,
           const float* __restrict__ vtstd, const float* __restrict__ icds,
           const float* __restrict__ inw, float* __restrict__ out, int B)
{
    __shared__ __align__(16) float gin[PPB * IN_STRIDE];
    __shared__ __align__(16) float lds[PPB * WSTRIDE];
    const int tid = threadIdx.x;
    const int praw = tid / LPP;
    const int r = tid - praw * LPP;            // 0..8
    const int p = (praw < PPB) ? praw : (PPB - 1);
    const int blk0 = blockIdx.x * PPB;
    const int b0 = blk0 + p;
    const bool valid = (praw < PPB) && (b0 < B);
    const int b = (b0 < B) ? b0 : (B - 1);
    float* L = lds + p * WSTRIDE;
    const float* gi = gin + p * IN_STRIDE;

    // ---- block-coalesced preload of step inputs into re-packed LDS slots
    //      (exactly TSTEPS=11 steps -> no slot overflow; R9 bug was t=11 spill)
    {
        const size_t dmax = (size_t)B * 11 - 1;
        for (int e = tid; e < PPB * 11; e += 64) {
            const int pp = e / 11, o = e - pp * 11;
            gin[pp * IN_STRIDE + o * 20] = dts[umin_sz((size_t)blk0 * 11 + e, dmax)];
        }
        const size_t wmax = (size_t)B * 72 - 1;
        for (int e = tid; e < PPB * 66; e += 64) {           // 11 steps x 6
            const int pp = e / 66, o = e - pp * 66;
            const int t = o / 6, k = o - t * 6;
            gin[pp * IN_STRIDE + t * 20 + 2 + k] =
                wa[umin_sz((size_t)blk0 * 72 + (size_t)pp * 72 + o, wmax)];
        }
        const size_t rmax = (size_t)B * 108 - 1;
        for (int e = tid; e < PPB * 99; e += 64) {           // 11 steps x 9
            const int pp = e / 99, o = e - pp * 99;
            const int t = o / 9, k = o - t * 9;
            gin[pp * IN_STRIDE + t * 20 + 8 + k] =
                Rc[umin_sz((size_t)blk0 * 108 + (size_t)pp * 108 + o, rmax)];
        }
    }

    // ---- preload update-phase operands into registers (latency hidden under scan)
    float h0v[9], h1v[9];
#pragma unroll
    for (int i = 0; i < 9; ++i) { h0v[i] = H0g[(size_t)b * 9 + i]; h1v[i] = H1g[(size_t)b * 9 + i]; }
    const int rc6 = (r < 6) ? r : 5;
    const float* hpr = (rc6 < 3) ? (H0g + (size_t)b * 9 + rc6 * 3)
                                 : (H1g + (size_t)b * 9 + (rc6 - 3) * 3);
    const float hr0 = hpr[0], hr1 = hpr[1], hr2 = hpr[2];
    const float sdv = (rc6 < 3) ? vrstd[(size_t)b * 3 + rc6] : vtstd[(size_t)b * 3 + (rc6 - 3)];
    const float rsa = (rc6 < 3) ? vrot[(size_t)b * 3 + rc6] : vtrans[(size_t)b * 3 + (rc6 - 3)];
    const float rsb = (rc6 < 3) ? prot[(size_t)b * 3 + rc6] : ptrans[(size_t)b * 3 + (rc6 - 3)];
    const float velv = vel[(size_t)b * 3 + ((r >= 6) ? (r - 6) : 0)];

    const float qcA = 1e-7f * exp10f(4.f * tanhf(inw[0]));
    const float qcB = 1e-7f * exp10f(4.f * tanhf(inw[1]));
    const float qcC = 1e-2f * exp10f(4.f * tanhf(inw[2]));
    const float qcD = 1e-3f * exp10f(4.f * tanhf(inw[3]));

    const float g0 = grav[(size_t)b*3+0], g1 = grav[(size_t)b*3+1], g2 = grav[(size_t)b*3+2];

    // Lane state: np = P[:, r] (dense); ncr = P[0:9, 9+r] (cross col);
    // d_br = P[9+r][9+r]  (bottom-right block stays EXACTLY diagonal: Phi rows
    // 9..17 are identity and truncated-Q's bb block is diagonal)
    float np[18], ncr[9];
#pragma unroll
    for (int k = 0; k < 18; ++k) np[k] = 0.f;
#pragma unroll
    for (int k = 0; k < 9; ++k) ncr[k] = 0.f;
    float d_br;
    { const float d0 = icds[r];     np[r] = d0*d0 + 1e-12f;
      const float d1 = icds[9 + r]; d_br  = d1*d1 + 1e-12f; }

    const int cls = (r < 3) ? 0 : ((r < 6) ? 1 : 2);
    const int c3 = r - 3 * cls;    // 0..2 within class

    __syncthreads();   // preload visible

    // current-step inputs (registers)
    float dt = gi[0];
    float w0, w1, w2, ar0, ar1, ar2, Rm[9];
    {
        const float2 qa = *(const float2*)&gi[2];
        const float2 qb = *(const float2*)&gi[4];
        const float2 qc = *(const float2*)&gi[6];
        w0 = qa.x; w1 = qa.y; w2 = qb.x; ar0 = qb.y; ar1 = qc.x; ar2 = qc.y;
        const float4 r0 = *(const float4*)&gi[8];
        const float4 r1 = *(const float4*)&gi[12];
        Rm[0]=r0.x; Rm[1]=r0.y; Rm[2]=r0.z; Rm[3]=r0.w;
        Rm[4]=r1.x; Rm[5]=r1.y; Rm[6]=r1.z; Rm[7]=r1.w;
        Rm[8]=gi[16];
    }

    for (int t = 0; t < TSTEPS; ++t) {
        // ---- prefetch t+1 inputs (LDS->reg)
        const int tn = (t + 1 < TSTEPS) ? (t + 1) : t;
        const float dt_n = gi[tn*20];
        const float2 nqa = *(const float2*)&gi[tn*20 + 2];
        const float2 nqb = *(const float2*)&gi[tn*20 + 4];
        const float2 nqc = *(const float2*)&gi[tn*20 + 6];
        const float4 nr0 = *(const float4*)&gi[tn*20 + 8];
        const float4 nr1 = *(const float4*)&gi[tn*20 + 12];
        const float nr8 = gi[tn*20 + 16];

        const float hdt2 = 0.5f * dt * dt;
        // a' = Rg + (acc - Rg)  (replicate reference rounding)
        const float Rg0 = Rm[0]*g0 + Rm[3]*g1 + Rm[6]*g2;
        const float Rg1 = Rm[1]*g0 + Rm[4]*g1 + Rm[7]*g2;
        const float Rg2 = Rm[2]*g0 + Rm[5]*g1 + Rm[8]*g2;
        const float a0 = Rg0 + (ar0 - Rg0);
        const float a1 = Rg1 + (ar1 - Rg1);
        const float a2 = Rg2 + (ar2 - Rg2);

        // ---- S parameters (theta <= ~0.06 -> 3-term Taylor, validated R4)
        const float p0 = dt*w0, p1 = dt*w1, p2 = dt*w2;
        const float th2 = p0*p0 + p1*p1 + p2*p2;
        const float th4 = th2 * th2;
        const float A  = 1.f - th2*(1.f/6.f)  + th4*(1.f/120.f);
        const float Bc = 0.5f - th2*(1.f/24.f) + th4*(1.f/720.f);
        float E[9];
        E[0] =  Bc*(p0*p0 - th2);  E[1] =  A*p2 + Bc*p0*p1;  E[2] = -A*p1 + Bc*p0*p2;
        E[3] = -A*p2 + Bc*p1*p0;   E[4] =  Bc*(p1*p1 - th2); E[5] =  A*p0 + Bc*p1*p2;
        E[6] =  A*p1 + Bc*p2*p0;   E[7] = -A*p0 + Bc*p2*p1;  E[8] =  Bc*(p2*p2 - th2);
        float N[9];
        N[0] = -(Rm[1]*a2 - Rm[2]*a1);  N[1] = -(Rm[2]*a0 - Rm[0]*a2);  N[2] = -(Rm[0]*a1 - Rm[1]*a0);
        N[3] = -(Rm[4]*a2 - Rm[5]*a1);  N[4] = -(Rm[5]*a0 - Rm[3]*a2);  N[5] = -(Rm[3]*a1 - Rm[4]*a0);
        N[6] = -(Rm[7]*a2 - Rm[8]*a1);  N[7] = -(Rm[8]*a0 - Rm[6]*a2);  N[8] = -(Rm[6]*a1 - Rm[7]*a0);
        float M2[9];
#pragma unroll
        for (int c = 0; c < 3; ++c) {
            const float n0 = N[c*3], n1 = N[c*3+1], n2 = N[c*3+2];
            M2[c*3+0] = dt*n0 - hdt2*(n1*w2 - n2*w1);
            M2[c*3+1] = dt*n1 - hdt2*(n2*w0 - n0*w2);
            M2[c*3+2] = dt*n2 - hdt2*(n0*w1 - n1*w0);
        }

        auto Smv = [&](const float v[18], float o[9]) {
            const float ev0 = E[0]*v[0] + E[1]*v[1] + E[2]*v[2];
            const float ev1 = E[3]*v[0] + E[4]*v[1] + E[5]*v[2];
            const float ev2 = E[6]*v[0] + E[7]*v[1] + E[8]*v[2];
            const float cx0 = w1*v[14] - w2*v[13];
            const float cx1 = w2*v[12] - w0*v[14];
            const float cx2 = w0*v[13] - w1*v[12];
            o[0] = ev0 - dt*v[12] + hdt2*cx0;
            o[1] = ev1 - dt*v[13] + hdt2*cx1;
            o[2] = ev2 - dt*v[14] + hdt2*cx2;
            const float nv0 = N[0]*v[0] + N[1]*v[1] + N[2]*v[2];
            const float nv1 = N[3]*v[0] + N[4]*v[1] + N[5]*v[2];
            const float nv2 = N[6]*v[0] + N[7]*v[1] + N[8]*v[2];
            const float rv0 = Rm[0]*v[15] + Rm[1]*v[16] + Rm[2]*v[17];
            const float rv1 = Rm[3]*v[15] + Rm[4]*v[16] + Rm[5]*v[17];
            const float rv2 = Rm[6]*v[15] + Rm[7]*v[16] + Rm[8]*v[17];
            o[3] = hdt2*nv0 + dt*v[6] - hdt2*v[9]  - hdt2*rv0;
            o[4] = hdt2*nv1 + dt*v[7] - hdt2*v[10] - hdt2*rv1;
            o[5] = hdt2*nv2 + dt*v[8] - hdt2*v[11] - hdt2*rv2;
            const float mv0 = M2[0]*v[0] + M2[1]*v[1] + M2[2]*v[2];
            const float mv1 = M2[3]*v[0] + M2[4]*v[1] + M2[5]*v[2];
            const float mv2 = M2[6]*v[0] + M2[7]*v[1] + M2[8]*v[2];
            const float nw0 = N[0]*v[12] + N[1]*v[13] + N[2]*v[14];
            const float nw1 = N[3]*v[12] + N[4]*v[13] + N[5]*v[14];
            const float nw2 = N[6]*v[12] + N[7]*v[13] + N[8]*v[14];
            o[6] = mv0 - dt*v[9]  - hdt2*nw0 - dt*rv0;
            o[7] = mv1 - dt*v[10] - hdt2*nw1 - dt*rv1;
            o[8] = mv2 - dt*v[11] - hdt2*nw2 - dt*rv2;
        };

        // ---- phase A
        // U column r = S * np  (full Smv)
        float uca[9];
        Smv(np, uca);

        // U column 9+r = S * (ncr ; d_br*e_{9+r})  — bb block diagonal, exact
        float ucb[9];
        {
            const float colR0 = sel3(c3, Rm[0], Rm[1], Rm[2]);
            const float colR1 = sel3(c3, Rm[3], Rm[4], Rm[5]);
            const float colR2 = sel3(c3, Rm[6], Rm[7], Rm[8]);
            const float colN0 = sel3(c3, N[0], N[1], N[2]);
            const float colN1 = sel3(c3, N[3], N[4], N[5]);
            const float colN2 = sel3(c3, N[6], N[7], N[8]);
            const float colK0 = sel3(c3, 0.f, -w2,  w1);   // skew(w) col c
            const float colK1 = sel3(c3,  w2, 0.f, -w0);
            const float colK2 = sel3(c3, -w1,  w0, 0.f);
            const float e0c = (c3 == 0) ? 1.f : 0.f;
            const float e1c = (c3 == 1) ? 1.f : 0.f;
            const float e2c = (c3 == 2) ? 1.f : 0.f;
            const float dbdt = d_br * dt, dbh = d_br * hdt2;

            const float s00 = (cls == 1) ? (-dbdt*e0c + dbh*colK0) : 0.f;
            const float s01 = (cls == 1) ? (-dbdt*e1c + dbh*colK1) : 0.f;
            const float s02 = (cls == 1) ? (-dbdt*e2c + dbh*colK2) : 0.f;
            const float s30 = (cls == 0) ? -dbh*e0c : ((cls == 2) ? -dbh*colR0 : 0.f);
            const float s31 = (cls == 0) ? -dbh*e1c : ((cls == 2) ? -dbh*colR1 : 0.f);
            const float s32 = (cls == 0) ? -dbh*e2c : ((cls == 2) ? -dbh*colR2 : 0.f);
            const float s60 = (cls == 0) ? -dbdt*e0c : ((cls == 1) ? -dbh*colN0 : -dbdt*colR0);
            const float s61 = (cls == 0) ? -dbdt*e1c : ((cls == 1) ? -dbh*colN1 : -dbdt*colR1);
            const float s62 = (cls == 0) ? -dbdt*e2c : ((cls == 1) ? -dbh*colN2 : -dbdt*colR2);

            ucb[0] = E[0]*ncr[0] + E[1]*ncr[1] + E[2]*ncr[2] + s00;
            ucb[1] = E[3]*ncr[0] + E[4]*ncr[1] + E[5]*ncr[2] + s01;
            ucb[2] = E[6]*ncr[0] + E[7]*ncr[1] + E[8]*ncr[2] + s02;
            ucb[3] = hdt2*(N[0]*ncr[0] + N[1]*ncr[1] + N[2]*ncr[2]) + dt*ncr[6] + s30;
            ucb[4] = hdt2*(N[3]*ncr[0] + N[4]*ncr[1] + N[5]*ncr[2]) + dt*ncr[7] + s31;
            ucb[5] = hdt2*(N[6]*ncr[0] + N[7]*ncr[1] + N[8]*ncr[2]) + dt*ncr[8] + s32;
            ucb[6] = M2[0]*ncr[0] + M2[1]*ncr[1] + M2[2]*ncr[2] + s60;
            ucb[7] = M2[3]*ncr[0] + M2[4]*ncr[1] + M2[5]*ncr[2] + s61;
            ucb[8] = M2[6]*ncr[0] + M2[7]*ncr[1] + M2[8]*ncr[2] + s62;
        }

#pragma unroll
        for (int i = 0; i < 9; ++i) {
            L[i*20 + r]     = uca[i];
            L[i*20 + 9 + r] = ucb[i];
        }
        __syncthreads();

        // ---- phase B: read U row r (issue first), independent Q cols fill the wait
        float ur[18];
        {
            const float4* up = (const float4*)&L[r*20];
            const float4 q0 = up[0], q1 = up[1], q2 = up[2], q3 = up[3];
            const float2 q4 = *(const float2*)&L[r*20 + 16];
            ur[0]=q0.x; ur[1]=q0.y; ur[2]=q0.z; ur[3]=q0.w;
            ur[4]=q1.x; ur[5]=q1.y; ur[6]=q1.z; ur[7]=q1.w;
            ur[8]=q2.x; ur[9]=q2.y; ur[10]=q2.z; ur[11]=q2.w;
            ur[12]=q3.x; ur[13]=q3.y; ur[14]=q3.z; ur[15]=q3.w;
            ur[16]=q4.x; ur[17]=q4.y;
        }

        // Q ≈ G qc Gᵀ dt (R8, validated): col r needs qcC·(R Rᵀ) col for r>=6
        const float rc0 = sel3(c3, Rm[0], Rm[3], Rm[6]);
        const float rc1 = sel3(c3, Rm[1], Rm[4], Rm[7]);
        const float rc2 = sel3(c3, Rm[2], Rm[5], Rm[8]);
        const float dq = dt * qcC;
        const float q0v = dq * (Rm[0]*rc0 + Rm[1]*rc1 + Rm[2]*rc2);
        const float q1v = dq * (Rm[3]*rc0 + Rm[4]*rc1 + Rm[5]*rc2);
        const float q2v = dq * (Rm[6]*rc0 + Rm[7]*rc1 + Rm[8]*rc2);

        // (U Sᵀ)[:,r] = S * (U row r)ᵀ   (USᵀ symmetric)
        float w9[9];
        Smv(ur, w9);

        // ---- assemble new P columns
#pragma unroll
        for (int i = 0; i < 9; ++i)
            np[i] = np[i] + uca[i] + ur[i] + w9[i];
        if (r < 3) np[r] += dt * qcA;
        if (r >= 6) { np[6] += q0v; np[7] += q1v; np[8] += q2v; }
#pragma unroll
        for (int i = 9; i < 18; ++i) np[i] += ur[i];

#pragma unroll
        for (int i = 0; i < 9; ++i) ncr[i] += ucb[i];
        if (r >= 3) d_br += dt * ((r < 6) ? qcB : qcD);

        __syncthreads();

        // rotate prefetched inputs
        dt = dt_n;
        w0 = nqa.x; w1 = nqa.y; w2 = nqb.x; ar0 = nqb.y; ar1 = nqc.x; ar2 = nqc.y;
        Rm[0]=nr0.x; Rm[1]=nr0.y; Rm[2]=nr0.z; Rm[3]=nr0.w;
        Rm[4]=nr1.x; Rm[5]=nr1.y; Rm[6]=nr1.z; Rm[7]=nr1.w;
        Rm[8]=nr8;
    }

    // ---------- update (operands preloaded; P row 9+r = (ncr ; d_br e_r)) ----------
    float phtA[6], phtB[6];
#pragma unroll
    for (int m = 0; m < 3; ++m) {
        phtA[m] = np[0]*h0v[m*3] + np[1]*h0v[m*3+1] + np[2]*h0v[m*3+2];
        phtB[m] = ncr[0]*h0v[m*3] + ncr[1]*h0v[m*3+1] + ncr[2]*h0v[m*3+2];
    }
#pragma unroll
    for (int m = 3; m < 6; ++m) {
        phtA[m] = np[0]*h1v[(m-3)*3] + np[1]*h1v[(m-3)*3+1] + np[2]*h1v[(m-3)*3+2] + np[m];
        phtB[m] = ncr[0]*h1v[(m-3)*3] + ncr[1]*h1v[(m-3)*3+1] + ncr[2]*h1v[(m-3)*3+2] + ncr[m];
    }
#pragma unroll
    for (int m = 0; m < 6; ++m) {
        L[PHT_OFF + r*8 + m]       = phtA[m];
        L[PHT_OFF + (9 + r)*8 + m] = phtB[m];
    }
    __syncthreads();

    if (valid && r < 6) {
        const float VIG = (float)(10.0 / (5.4 * 5.4));
#pragma unroll
        for (int n = 0; n < 6; ++n) {
            float v = hr0 * L[PHT_OFF + 0*8 + n] + hr1 * L[PHT_OFF + 1*8 + n]
                    + hr2 * L[PHT_OFF + 2*8 + n];
            if (r >= 3) v += phtA[n];
            if (n == r) v += VIG * exp10f(3.f * tanhf(sdv));
            L[S6_OFF + r*8 + n] = v;
        }
        L[S6_OFF + r*8 + 6] = (r < 3) ? (rsa - rsb) : (rsa * 5.4f - rsb);
    }
    __syncthreads();

    // 6x6 solve in registers: lane r==0 per problem (7 per wave, lockstep)
    if (valid && r == 0) {
        float a[6][7];
        const float* Sb = &L[S6_OFF];
#pragma unroll
        for (int m = 0; m < 6; ++m) {
            const float4 q0 = *(const float4*)&Sb[m*8];
            const float4 q1 = *(const float4*)&Sb[m*8 + 4];
            a[m][0]=q0.x; a[m][1]=q0.y; a[m][2]=q0.z; a[m][3]=q0.w;
            a[m][4]=q1.x; a[m][5]=q1.y; a[m][6]=q1.z;
        }
#pragma unroll
        for (int k = 0; k < 6; ++k) {
#pragma unroll
            for (int j = k + 1; j < 6; ++j) {
                const bool c = fabsf(a[j][k]) > fabsf(a[k][k]);
#pragma unroll
                for (int cc = k; cc < 7; ++cc) {
                    const float hi = c ? a[j][cc] : a[k][cc];
                    const float lo = c ? a[k][cc] : a[j][cc];
                    a[k][cc] = hi; a[j][cc] = lo;
                }
            }
            const float inv = 1.f / a[k][k];
#pragma unroll
            for (int j = 0; j < 6; ++j) {
                if (j == k) continue;
                const float f = a[j][k] * inv;
#pragma unroll
                for (int cc = k + 1; cc < 7; ++cc) a[j][cc] -= f * a[k][cc];
            }
        }
#pragma unroll
        for (int m = 0; m < 6; ++m) L[Y_OFF + m] = a[m][6] / a[m][m];
    }
    __syncthreads();

    float ym[6];
#pragma unroll
    for (int m = 0; m < 6; ++m) ym[m] = L[Y_OFF + m];
    float estr = 0.f, est9 = 0.f;
#pragma unroll
    for (int m = 0; m < 6; ++m) { estr += phtA[m]*ym[m]; est9 += phtB[m]*ym[m]; }
    if (valid) {
        L[EST_OFF + r] = estr;
        if (r < 3) L[EST_OFF + 9 + r] = est9;
    }
    __syncthreads();

    const float e0 = L[EST_OFF + 0], e1 = L[EST_OFF + 1], e2 = L[EST_OFF + 2];
    if (valid) {
        float o;
        if (r < 3) {
            o = rsb + hr0*e0 + hr1*e1 + hr2*e2;
        } else if (r < 6) {
            o = rsb + hr0*e0 + hr1*e1 + hr2*e2 + estr;
        } else {
            o = velv + estr;
        }
        out[(size_t)b*12 + r] = o;
        if (r < 3) out[(size_t)b*12 + 9 + r] = ((r==0)?g0:((r==1)?g1:g2)) + est9;
    }
}

extern "C" void kernel_launch(void* const* d_in, const int* in_sizes, int n_in,
                              void* d_out, int out_size, void* d_ws, size_t ws_size,
                              hipStream_t stream) {
    const float* dts    = (const float*)d_in[0];
    const float* wa     = (const float*)d_in[1];
    const float* Rc     = (const float*)d_in[2];
    const float* vel    = (const float*)d_in[3];
    const float* grav   = (const float*)d_in[4];
    const float* H0g    = (const float*)d_in[5];
    const float* H1g    = (const float*)d_in[6];
    const float* prot   = (const float*)d_in[7];
    const float* ptrans = (const float*)d_in[8];
    const float* vrot   = (const float*)d_in[9];
    const float* vtrans = (const float*)d_in[10];
    const float* vrstd  = (const float*)d_in[11];
    const float* vtstd  = (const float*)d_in[12];
    const float* icds   = (const float*)d_in[13];
    const float* inw    = (const float*)d_in[14];
    float* outp = (float*)d_out;

    const int B = in_sizes[0] / TSTEPS;
    const int grid = (B + PPB - 1) / PPB;
    hipLaunchKernelGGL(ekf_kernel, dim3(grid), dim3(64), 0, stream,
                       dts, wa, Rc, vel, grav, H0g, H1g, prot, ptrans,
                       vrot, vtrans, vrstd, vtstd, icds, inw, outp, B);
}